// Round 1
// baseline (607.380 us; speedup 1.0000x reference)
//
#include <hip/hip_runtime.h>

#define Bv 32
#define Sv 128
#define Tv 2000
#define Dv 768
#define Hv 256
#define Rv 50

// ---------------------------------------------------------------------------
// Kernel 1: per-token feature chain.
// block = 256 threads, one token per block. grid = B*S = 4096.
// ---------------------------------------------------------------------------
__global__ __launch_bounds__(256) void tok_feats(
    const int* __restrict__ words, const int* __restrict__ pos_ids,
    const float* __restrict__ audio, const float* __restrict__ st,
    const float* __restrict__ et,
    const float* __restrict__ word_W, const float* __restrict__ pos_W,
    const float* __restrict__ audio_w, const float* __restrict__ audio_b,
    const float* __restrict__ m1w, const float* __restrict__ m1b,
    const float* __restrict__ m2w, const float* __restrict__ m2b,
    const float* __restrict__ aw, const float* __restrict__ ab,
    const float* __restrict__ rw, const float* __restrict__ rb,
    float* __restrict__ head, float* __restrict__ dep,
    float* __restrict__ relh, float* __restrict__ reld)
{
  const int tok = blockIdx.x;
  const int b = tok >> 7;          // tok / S
  const int tid = threadIdx.x;

  __shared__ float smean[768];
  __shared__ float sx0[252];
  __shared__ float sh1[256];
  __shared__ float sx[256];
  __shared__ float shead[256];

  // --- audio segment mean (matches reference truncation/clip semantics) ---
  const float stime = st[tok], etime = et[tok];
  const int si = (int)(stime * 50.0f);   // trunc == floor for >= 0
  const int ei = (int)(etime * 50.0f);
  const bool valid = (ei > si) && (ei <= Tv);
  const int sc = min(max(si, 0), Tv);
  const int ec = min(max(ei, 0), Tv);
  const float inv = 1.0f / (float)max(ec - sc, 1);

  {
    float a0 = 0.f, a1 = 0.f, a2 = 0.f;
    const float* abase = audio + (size_t)b * Tv * Dv;
    for (int t = sc; t < ec; ++t) {
      const float* row = abase + (size_t)t * Dv;
      a0 += row[tid];
      a1 += row[tid + 256];
      a2 += row[tid + 512];
    }
    const float m = valid ? inv : 0.f;
    smean[tid]       = a0 * m;
    smean[tid + 256] = a1 * m;
    smean[tid + 512] = a2 * m;
  }

  // word / pos embedding gathers (overlap with mean write, one sync covers)
  if (tid < 100) {
    sx0[tid] = word_W[(size_t)words[tok] * 100 + tid];
  } else if (tid < 150) {
    sx0[tid] = pos_W[pos_ids[tok] * 50 + (tid - 100)];
  }
  __syncthreads();

  // audio projection: 768 -> 100 (threads 0..99, float4 weight loads)
  if (tid < 100) {
    float acc = audio_b[tid];
    const float4* wr = (const float4*)(audio_w + tid * 768);
#pragma unroll 4
    for (int k = 0; k < 192; ++k) {
      float4 v = wr[k];
      acc += v.x * smean[4*k] + v.y * smean[4*k+1]
           + v.z * smean[4*k+2] + v.w * smean[4*k+3];
    }
    sx0[150 + tid] = acc;
  }
  __syncthreads();

  // mlp1: 250 -> 256, relu. 250 floats = 1000 B rows -> float2 aligned.
  {
    float acc = m1b[tid];
    const float2* wr = (const float2*)(m1w + tid * 250);
#pragma unroll 5
    for (int k = 0; k < 125; ++k) {
      float2 v = wr[k];
      acc += v.x * sx0[2*k] + v.y * sx0[2*k+1];
    }
    sh1[tid] = fmaxf(acc, 0.f);
  }
  __syncthreads();

  // mlp2: 256 -> 256, relu. Also the "dep" features.
  {
    float acc = m2b[tid];
    const float4* wr = (const float4*)(m2w + (size_t)tid * 256);
#pragma unroll 4
    for (int k = 0; k < 64; ++k) {
      float4 v = wr[k];
      acc += v.x * sh1[4*k] + v.y * sh1[4*k+1]
           + v.z * sh1[4*k+2] + v.w * sh1[4*k+3];
    }
    float xv = fmaxf(acc, 0.f);
    sx[tid] = xv;
    dep[(size_t)tok * Hv + tid] = xv;
  }
  __syncthreads();

  // arc head: 256 -> 256
  {
    float acc = ab[tid];
    const float4* wr = (const float4*)(aw + (size_t)tid * 256);
#pragma unroll 4
    for (int k = 0; k < 64; ++k) {
      float4 v = wr[k];
      acc += v.x * sx[4*k] + v.y * sx[4*k+1]
           + v.z * sx[4*k+2] + v.w * sx[4*k+3];
    }
    shead[tid] = acc;
    head[(size_t)tok * Hv + tid] = acc;
  }
  __syncthreads();

  // rel projections: rel_h from head (fold rel_b in), rel_d from x.
  if (tid < Rv) {
    float acc = rb[tid];
    const float4* wr = (const float4*)(rw + tid * (2 * Hv));
#pragma unroll 4
    for (int k = 0; k < 64; ++k) {
      float4 v = wr[k];
      acc += v.x * shead[4*k] + v.y * shead[4*k+1]
           + v.z * shead[4*k+2] + v.w * shead[4*k+3];
    }
    relh[(size_t)tok * Rv + tid] = acc;
  } else if (tid >= 64 && tid < 64 + Rv) {
    const int r = tid - 64;
    float acc = 0.f;
    const float4* wr = (const float4*)(rw + r * (2 * Hv) + Hv);
#pragma unroll 4
    for (int k = 0; k < 64; ++k) {
      float4 v = wr[k];
      acc += v.x * sx[4*k] + v.y * sx[4*k+1]
           + v.z * sx[4*k+2] + v.w * sx[4*k+3];
    }
    reld[(size_t)tok * Rv + r] = acc;
  }
}

// ---------------------------------------------------------------------------
// Kernel 2: arc_scores[b,i,j] = dot(head[b,i], dep[b,j]).
// 32x32 output tile per block, K staged in 32-wide LDS chunks.
// grid = B * 16, block = 256.
// ---------------------------------------------------------------------------
__global__ __launch_bounds__(256) void arc_kernel(
    const float* __restrict__ head, const float* __restrict__ dep,
    float* __restrict__ out)
{
  const int blk = blockIdx.x;
  const int b = blk >> 4;
  const int tile = blk & 15;
  const int i0 = (tile >> 2) * 32;
  const int j0 = (tile & 3) * 32;

  __shared__ float sh[32][33];
  __shared__ float sd[32][33];

  const int tid = threadIdx.x;
  const int r = tid >> 3;          // 0..31
  const int c = (tid & 7) << 2;    // 0,4,...,28
  const int ty = tid >> 4;         // 0..15
  const int tx = tid & 15;         // 0..15

  float acc00 = 0.f, acc01 = 0.f, acc10 = 0.f, acc11 = 0.f;
  const float* hb = head + (size_t)(b * Sv + i0) * Hv;
  const float* db = dep + (size_t)(b * Sv + j0) * Hv;

  for (int k0 = 0; k0 < Hv; k0 += 32) {
    float4 hv = *(const float4*)(hb + (size_t)r * Hv + k0 + c);
    float4 dv = *(const float4*)(db + (size_t)r * Hv + k0 + c);
    __syncthreads();
    sh[r][c] = hv.x; sh[r][c+1] = hv.y; sh[r][c+2] = hv.z; sh[r][c+3] = hv.w;
    sd[r][c] = dv.x; sd[r][c+1] = dv.y; sd[r][c+2] = dv.z; sd[r][c+3] = dv.w;
    __syncthreads();
#pragma unroll
    for (int kk = 0; kk < 32; ++kk) {
      float h0 = sh[ty][kk],      h1 = sh[ty + 16][kk];
      float d0 = sd[tx][kk],      d1 = sd[tx + 16][kk];
      acc00 += h0 * d0; acc01 += h0 * d1;
      acc10 += h1 * d0; acc11 += h1 * d1;
    }
  }

  float* ob = out + (size_t)b * Sv * Sv;
  ob[(i0 + ty) * Sv + j0 + tx]           = acc00;
  ob[(i0 + ty) * Sv + j0 + tx + 16]      = acc01;
  ob[(i0 + ty + 16) * Sv + j0 + tx]      = acc10;
  ob[(i0 + ty + 16) * Sv + j0 + tx + 16] = acc11;
}

// ---------------------------------------------------------------------------
// Kernel 3: rel_scores[b,i,j,r] = relh[b,i,r] + reld[b,j,r]  (rel_b folded).
// One block per (b,i); reld[b] staged in LDS; coalesced float2 stores.
// grid = B*S = 4096, block = 256.
// ---------------------------------------------------------------------------
__global__ __launch_bounds__(256) void rel_kernel(
    const float* __restrict__ relh, const float* __restrict__ reld,
    float* __restrict__ out)
{
  const int bi = blockIdx.x;       // b*S + i
  const int b = bi >> 7;
  const int tid = threadIdx.x;

  __shared__ float srd[Sv * Rv];   // 6400 floats = 25.6 KB
  __shared__ float shi[Rv];

  const float4* rd4 = (const float4*)(reld + (size_t)b * Sv * Rv);
  float4* s4 = (float4*)srd;
  for (int n = tid; n < (Sv * Rv / 4); n += 256) s4[n] = rd4[n];
  if (tid < Rv) shi[tid] = relh[(size_t)bi * Rv + tid];
  __syncthreads();

  float2* out2 = (float2*)(out + (size_t)bi * Sv * Rv);
  for (int n = tid; n < (Sv * Rv / 2); n += 256) {
    const int j = n / 25;
    const int r = (n - j * 25) * 2;
    const float* rdj = srd + j * Rv;
    float2 v;
    v.x = shi[r]     + rdj[r];
    v.y = shi[r + 1] + rdj[r + 1];
    out2[n] = v;
  }
}

// ---------------------------------------------------------------------------
extern "C" void kernel_launch(void* const* d_in, const int* in_sizes, int n_in,
                              void* d_out, int out_size, void* d_ws, size_t ws_size,
                              hipStream_t stream) {
  const int*   words   = (const int*)d_in[0];
  const int*   pos_ids = (const int*)d_in[1];
  const float* audio   = (const float*)d_in[2];
  const float* st      = (const float*)d_in[3];
  const float* et      = (const float*)d_in[4];
  const float* word_W  = (const float*)d_in[5];
  const float* pos_W   = (const float*)d_in[6];
  const float* audio_w = (const float*)d_in[7];
  const float* audio_b = (const float*)d_in[8];
  const float* m1w     = (const float*)d_in[9];
  const float* m1b     = (const float*)d_in[10];
  const float* m2w     = (const float*)d_in[11];
  const float* m2b     = (const float*)d_in[12];
  const float* aw      = (const float*)d_in[13];
  const float* ab      = (const float*)d_in[14];
  const float* rw      = (const float*)d_in[15];
  const float* rb      = (const float*)d_in[16];

  float* out = (float*)d_out;
  float* ws = (float*)d_ws;

  const size_t NT = (size_t)Bv * Sv;       // 4096 tokens
  float* head = ws;                         // NT*256
  float* dep  = head + NT * Hv;             // NT*256
  float* relh = dep + NT * Hv;              // NT*50
  float* reld = relh + NT * Rv;             // NT*50
  // total: 2*NT*256 + 2*NT*50 floats = ~9.6 MB of d_ws

  tok_feats<<<(int)NT, 256, 0, stream>>>(
      words, pos_ids, audio, st, et, word_W, pos_W, audio_w, audio_b,
      m1w, m1b, m2w, m2b, aw, ab, rw, rb, head, dep, relh, reld);

  arc_kernel<<<Bv * 16, 256, 0, stream>>>(head, dep, out);

  rel_kernel<<<(int)NT, 256, 0, stream>>>(relh, reld, out + (size_t)Bv * Sv * Sv);
}

// Round 2
// 250.102 us; speedup vs baseline: 2.4285x; 2.4285x over previous
//
#include <hip/hip_runtime.h>

#define Bv 32
#define Sv 128
#define Tv 2000
#define Dv 768
#define Hv 256
#define Rv 50

// ---------------------------------------------------------------------------
// Kernel 1: audio segment mean (frame-parallel waves) + word/pos gathers.
// One block per token, 256 threads = 4 frame-groups x 64 lanes.
// Lane l covers dims {4l..4l+3} + {256,512} offsets (3 float4 accumulators).
// ---------------------------------------------------------------------------
__global__ __launch_bounds__(256) void seg_mean(
    const int* __restrict__ words, const int* __restrict__ pos_ids,
    const float* __restrict__ audio, const float* __restrict__ st,
    const float* __restrict__ et,
    const float* __restrict__ word_W, const float* __restrict__ pos_W,
    float* __restrict__ smean, float* __restrict__ x0)
{
  const int tok = blockIdx.x;
  const int b = tok >> 7;
  const int tid = threadIdx.x;
  const int g = tid >> 6;          // frame group 0..3
  const int l = tid & 63;

  __shared__ float sgrp[4][768];

  const float stime = st[tok], etime = et[tok];
  const int si = (int)(stime * 50.0f);   // trunc == floor for >= 0
  const int ei = (int)(etime * 50.0f);
  const bool valid = (ei > si) && (ei <= Tv);
  const int sc = min(max(si, 0), Tv);
  const int ec = min(max(ei, 0), Tv);
  const float m = valid ? (1.0f / (float)max(ec - sc, 1)) : 0.0f;

  float4 a0 = {0,0,0,0}, a1 = {0,0,0,0}, a2 = {0,0,0,0};
  const float* abase = audio + (size_t)b * Tv * Dv + l * 4;

  int t = sc + g;
  for (; t + 4 < ec; t += 8) {
    const float* r0 = abase + (size_t)t * Dv;
    const float* r1 = abase + (size_t)(t + 4) * Dv;
    float4 u0 = *(const float4*)(r0);
    float4 u1 = *(const float4*)(r0 + 256);
    float4 u2 = *(const float4*)(r0 + 512);
    float4 v0 = *(const float4*)(r1);
    float4 v1 = *(const float4*)(r1 + 256);
    float4 v2 = *(const float4*)(r1 + 512);
    a0.x += u0.x + v0.x; a0.y += u0.y + v0.y; a0.z += u0.z + v0.z; a0.w += u0.w + v0.w;
    a1.x += u1.x + v1.x; a1.y += u1.y + v1.y; a1.z += u1.z + v1.z; a1.w += u1.w + v1.w;
    a2.x += u2.x + v2.x; a2.y += u2.y + v2.y; a2.z += u2.z + v2.z; a2.w += u2.w + v2.w;
  }
  if (t < ec) {
    const float* r0 = abase + (size_t)t * Dv;
    float4 u0 = *(const float4*)(r0);
    float4 u1 = *(const float4*)(r0 + 256);
    float4 u2 = *(const float4*)(r0 + 512);
    a0.x += u0.x; a0.y += u0.y; a0.z += u0.z; a0.w += u0.w;
    a1.x += u1.x; a1.y += u1.y; a1.z += u1.z; a1.w += u1.w;
    a2.x += u2.x; a2.y += u2.y; a2.z += u2.z; a2.w += u2.w;
  }

  *(float4*)&sgrp[g][l * 4]       = a0;
  *(float4*)&sgrp[g][256 + l * 4] = a1;
  *(float4*)&sgrp[g][512 + l * 4] = a2;
  __syncthreads();

  // reduce 4 groups, scale, store (coalesced)
  float* srow = smean + (size_t)tok * Dv;
#pragma unroll
  for (int s = 0; s < 3; ++s) {
    const int d = tid + s * 256;
    const float v = sgrp[0][d] + sgrp[1][d] + sgrp[2][d] + sgrp[3][d];
    srow[d] = v * m;
  }

  // word / pos embedding gathers into x0[:, 0:150]; zero the K-pad tail.
  if (tid < 100) {
    x0[(size_t)tok * 256 + tid] = word_W[(size_t)words[tok] * 100 + tid];
  } else if (tid < 150) {
    x0[(size_t)tok * 256 + tid] = pos_W[pos_ids[tok] * 50 + (tid - 100)];
  } else if (tid >= 250) {
    x0[(size_t)tok * 256 + tid] = 0.0f;   // cols 250..255 zero pad
  }
}

// ---------------------------------------------------------------------------
// Prepack: pad mlp1_w [256][250] -> [256][256] with zero columns 250..255.
// ---------------------------------------------------------------------------
__global__ __launch_bounds__(256) void pad_m1(const float* __restrict__ m1w,
                                              float* __restrict__ wpad)
{
  const int idx = blockIdx.x * 256 + threadIdx.x;   // 65536 total
  const int r = idx >> 8, c = idx & 255;
  wpad[idx] = (c < 250) ? m1w[r * 250 + c] : 0.0f;
}

// ---------------------------------------------------------------------------
// Register-tiled fp32 GEMM: C[M=4096, N] = A[M,K] @ W[N,K]^T (+bias, +relu).
// Block 256 threads, 64x64 tile, 4x4 per thread, K staged in 16-chunks,
// stored k-major in LDS with 68-float row stride (16B aligned, 2-way banks).
// grid = (M/64, ceil(N/64)). C written at column offset c0 with ldc stride.
// ---------------------------------------------------------------------------
template<bool BIAS, bool RELU>
__global__ __launch_bounds__(256) void gemm_tn(
    const float* __restrict__ A, int lda,
    const float* __restrict__ W, int ldw,
    const float* __restrict__ bias,
    float* __restrict__ C, int ldc, int c0,
    int N, int K)
{
  const int mt = blockIdx.x;
  const int nt = blockIdx.y;
  const int tid = threadIdx.x;
  const int tm = tid >> 4;          // 0..15
  const int tn = tid & 15;          // 0..15

  __shared__ float sA[16][68];
  __shared__ float sB[16][68];

  float acc[4][4] = {};

  const int row0 = mt * 64;
  const int n0 = nt * 64;
  const int tok = tid >> 2;         // 0..63 (staging row)
  const int kq = (tid & 3) << 2;    // 0,4,8,12 (staging k offset)

  for (int k0 = 0; k0 < K; k0 += 16) {
    const float4 av = *(const float4*)(A + (size_t)(row0 + tok) * lda + k0 + kq);
    float4 bv = {0,0,0,0};
    if (n0 + tok < N)
      bv = *(const float4*)(W + (size_t)(n0 + tok) * ldw + k0 + kq);
    __syncthreads();
    sA[kq + 0][tok] = av.x; sA[kq + 1][tok] = av.y;
    sA[kq + 2][tok] = av.z; sA[kq + 3][tok] = av.w;
    sB[kq + 0][tok] = bv.x; sB[kq + 1][tok] = bv.y;
    sB[kq + 2][tok] = bv.z; sB[kq + 3][tok] = bv.w;
    __syncthreads();
#pragma unroll
    for (int kk = 0; kk < 16; ++kk) {
      const float4 a = *(const float4*)&sA[kk][tm * 4];
      const float4 b = *(const float4*)&sB[kk][tn * 4];
      acc[0][0] += a.x * b.x; acc[0][1] += a.x * b.y;
      acc[0][2] += a.x * b.z; acc[0][3] += a.x * b.w;
      acc[1][0] += a.y * b.x; acc[1][1] += a.y * b.y;
      acc[1][2] += a.y * b.z; acc[1][3] += a.y * b.w;
      acc[2][0] += a.z * b.x; acc[2][1] += a.z * b.y;
      acc[2][2] += a.z * b.z; acc[2][3] += a.z * b.w;
      acc[3][0] += a.w * b.x; acc[3][1] += a.w * b.y;
      acc[3][2] += a.w * b.z; acc[3][3] += a.w * b.w;
    }
  }

#pragma unroll
  for (int i = 0; i < 4; ++i) {
    const int row = row0 + tm * 4 + i;
    float* crow = C + (size_t)row * ldc + c0;
#pragma unroll
    for (int j = 0; j < 4; ++j) {
      const int col = n0 + tn * 4 + j;
      if (col < N) {
        float v = acc[i][j];
        if (BIAS) v += bias[col];
        if (RELU) v = fmaxf(v, 0.0f);
        crow[col] = v;
      }
    }
  }
}

// ---------------------------------------------------------------------------
// arc_scores[b,i,j] = dot(head[b,i], dep[b,j]). 32x32 tile per block.
// ---------------------------------------------------------------------------
__global__ __launch_bounds__(256) void arc_kernel(
    const float* __restrict__ head, const float* __restrict__ dep,
    float* __restrict__ out)
{
  const int blk = blockIdx.x;
  const int b = blk >> 4;
  const int tile = blk & 15;
  const int i0 = (tile >> 2) * 32;
  const int j0 = (tile & 3) * 32;

  __shared__ float sh[32][33];
  __shared__ float sd[32][33];

  const int tid = threadIdx.x;
  const int r = tid >> 3;
  const int c = (tid & 7) << 2;
  const int ty = tid >> 4;
  const int tx = tid & 15;

  float acc00 = 0.f, acc01 = 0.f, acc10 = 0.f, acc11 = 0.f;
  const float* hb = head + (size_t)(b * Sv + i0) * Hv;
  const float* db = dep + (size_t)(b * Sv + j0) * Hv;

  for (int k0 = 0; k0 < Hv; k0 += 32) {
    float4 hv = *(const float4*)(hb + (size_t)r * Hv + k0 + c);
    float4 dv = *(const float4*)(db + (size_t)r * Hv + k0 + c);
    __syncthreads();
    sh[r][c] = hv.x; sh[r][c+1] = hv.y; sh[r][c+2] = hv.z; sh[r][c+3] = hv.w;
    sd[r][c] = dv.x; sd[r][c+1] = dv.y; sd[r][c+2] = dv.z; sd[r][c+3] = dv.w;
    __syncthreads();
#pragma unroll
    for (int kk = 0; kk < 32; ++kk) {
      float h0 = sh[ty][kk],  h1 = sh[ty + 16][kk];
      float d0 = sd[tx][kk],  d1 = sd[tx + 16][kk];
      acc00 += h0 * d0; acc01 += h0 * d1;
      acc10 += h1 * d0; acc11 += h1 * d1;
    }
  }

  float* ob = out + (size_t)b * Sv * Sv;
  ob[(i0 + ty) * Sv + j0 + tx]           = acc00;
  ob[(i0 + ty) * Sv + j0 + tx + 16]      = acc01;
  ob[(i0 + ty + 16) * Sv + j0 + tx]      = acc10;
  ob[(i0 + ty + 16) * Sv + j0 + tx + 16] = acc11;
}

// ---------------------------------------------------------------------------
// rel_scores[b,i,j,r] = relh[b,i,r] + reld[b,j,r]  (rel_b folded into relh).
// ---------------------------------------------------------------------------
__global__ __launch_bounds__(256) void rel_kernel(
    const float* __restrict__ relh, const float* __restrict__ reld,
    float* __restrict__ out)
{
  const int bi = blockIdx.x;
  const int b = bi >> 7;
  const int tid = threadIdx.x;

  __shared__ float srd[Sv * Rv];
  __shared__ float shi[Rv];

  const float4* rd4 = (const float4*)(reld + (size_t)b * Sv * Rv);
  float4* s4 = (float4*)srd;
  for (int n = tid; n < (Sv * Rv / 4); n += 256) s4[n] = rd4[n];
  if (tid < Rv) shi[tid] = relh[(size_t)bi * Rv + tid];
  __syncthreads();

  float2* out2 = (float2*)(out + (size_t)bi * Sv * Rv);
  for (int n = tid; n < (Sv * Rv / 2); n += 256) {
    const int j = n / 25;
    const int r = (n - j * 25) * 2;
    const float* rdj = srd + j * Rv;
    float2 v;
    v.x = shi[r]     + rdj[r];
    v.y = shi[r + 1] + rdj[r + 1];
    out2[n] = v;
  }
}

// ---------------------------------------------------------------------------
extern "C" void kernel_launch(void* const* d_in, const int* in_sizes, int n_in,
                              void* d_out, int out_size, void* d_ws, size_t ws_size,
                              hipStream_t stream) {
  const int*   words   = (const int*)d_in[0];
  const int*   pos_ids = (const int*)d_in[1];
  const float* audio   = (const float*)d_in[2];
  const float* st      = (const float*)d_in[3];
  const float* et      = (const float*)d_in[4];
  const float* word_W  = (const float*)d_in[5];
  const float* pos_W   = (const float*)d_in[6];
  const float* audio_w = (const float*)d_in[7];
  const float* audio_b = (const float*)d_in[8];
  const float* m1w     = (const float*)d_in[9];
  const float* m1b     = (const float*)d_in[10];
  const float* m2w     = (const float*)d_in[11];
  const float* m2b     = (const float*)d_in[12];
  const float* aw      = (const float*)d_in[13];
  const float* ab      = (const float*)d_in[14];
  const float* rw      = (const float*)d_in[15];
  const float* rb      = (const float*)d_in[16];

  float* out = (float*)d_out;
  float* ws = (float*)d_ws;

  const size_t NT = (size_t)Bv * Sv;            // 4096 tokens
  float* smean = ws;                            // NT*768
  float* x0    = smean + NT * Dv;               // NT*256
  float* h1    = x0    + NT * 256;              // NT*256
  float* xfeat = h1    + NT * 256;              // NT*256 (dep)
  float* head  = xfeat + NT * 256;              // NT*256
  float* relh  = head  + NT * 256;              // NT*50
  float* reld  = relh  + NT * Rv;               // NT*50
  float* wpad  = reld  + NT * Rv;               // 256*256
  // total ~31.3 MB of d_ws

  seg_mean<<<(int)NT, 256, 0, stream>>>(
      words, pos_ids, audio, st, et, word_W, pos_W, smean, x0);

  pad_m1<<<256, 256, 0, stream>>>(m1w, wpad);

  // audio projection: x0[:, 150:250] = smean @ audio_w.T + audio_b
  gemm_tn<true, false><<<dim3(64, 2), 256, 0, stream>>>(
      smean, Dv, audio_w, Dv, audio_b, x0, 256, 150, 100, Dv);

  // mlp1: h1 = relu(x0 @ wpad.T + m1b)   (K padded 250->256)
  gemm_tn<true, true><<<dim3(64, 4), 256, 0, stream>>>(
      x0, 256, wpad, 256, m1b, h1, 256, 0, 256, 256);

  // mlp2: xfeat = relu(h1 @ m2w.T + m2b)
  gemm_tn<true, true><<<dim3(64, 4), 256, 0, stream>>>(
      h1, 256, m2w, 256, m2b, xfeat, 256, 0, 256, 256);

  // arc head: head = xfeat @ aw.T + ab
  gemm_tn<true, false><<<dim3(64, 4), 256, 0, stream>>>(
      xfeat, 256, aw, 256, ab, head, 256, 0, 256, 256);

  // rel projections
  gemm_tn<true, false><<<dim3(64, 1), 256, 0, stream>>>(
      head, 256, rw, 2 * Hv, rb, relh, Rv, 0, Rv, 256);
  gemm_tn<false, false><<<dim3(64, 1), 256, 0, stream>>>(
      xfeat, 256, rw + Hv, 2 * Hv, (const float*)nullptr, reld, Rv, 0, Rv, 256);

  arc_kernel<<<Bv * 16, 256, 0, stream>>>(head, xfeat, out);

  rel_kernel<<<(int)NT, 256, 0, stream>>>(relh, reld, out + (size_t)Bv * Sv * Sv);
}

// Round 3
// 229.284 us; speedup vs baseline: 2.6490x; 1.0908x over previous
//
#include <hip/hip_runtime.h>

#define Bv 32
#define Sv 128
#define Tv 2000
#define Dv 768
#define Hv 256
#define Rv 50

// ---------------------------------------------------------------------------
// Kernel 1: audio segment mean (frame-parallel waves) + word/pos gathers.
// One block per token, 256 threads = 4 frame-groups x 64 lanes.
// ---------------------------------------------------------------------------
__global__ __launch_bounds__(256) void seg_mean(
    const int* __restrict__ words, const int* __restrict__ pos_ids,
    const float* __restrict__ audio, const float* __restrict__ st,
    const float* __restrict__ et,
    const float* __restrict__ word_W, const float* __restrict__ pos_W,
    float* __restrict__ smean, float* __restrict__ x0)
{
  const int tok = blockIdx.x;
  const int b = tok >> 7;
  const int tid = threadIdx.x;
  const int g = tid >> 6;          // frame group 0..3
  const int l = tid & 63;

  __shared__ float sgrp[4][768];

  const float stime = st[tok], etime = et[tok];
  const int si = (int)(stime * 50.0f);   // trunc == floor for >= 0
  const int ei = (int)(etime * 50.0f);
  const bool valid = (ei > si) && (ei <= Tv);
  const int sc = min(max(si, 0), Tv);
  const int ec = min(max(ei, 0), Tv);
  const float m = valid ? (1.0f / (float)max(ec - sc, 1)) : 0.0f;

  float4 a0 = {0,0,0,0}, a1 = {0,0,0,0}, a2 = {0,0,0,0};
  const float* abase = audio + (size_t)b * Tv * Dv + l * 4;

  int t = sc + g;
  for (; t + 4 < ec; t += 8) {
    const float* r0 = abase + (size_t)t * Dv;
    const float* r1 = abase + (size_t)(t + 4) * Dv;
    float4 u0 = *(const float4*)(r0);
    float4 u1 = *(const float4*)(r0 + 256);
    float4 u2 = *(const float4*)(r0 + 512);
    float4 v0 = *(const float4*)(r1);
    float4 v1 = *(const float4*)(r1 + 256);
    float4 v2 = *(const float4*)(r1 + 512);
    a0.x += u0.x + v0.x; a0.y += u0.y + v0.y; a0.z += u0.z + v0.z; a0.w += u0.w + v0.w;
    a1.x += u1.x + v1.x; a1.y += u1.y + v1.y; a1.z += u1.z + v1.z; a1.w += u1.w + v1.w;
    a2.x += u2.x + v2.x; a2.y += u2.y + v2.y; a2.z += u2.z + v2.z; a2.w += u2.w + v2.w;
  }
  if (t < ec) {
    const float* r0 = abase + (size_t)t * Dv;
    float4 u0 = *(const float4*)(r0);
    float4 u1 = *(const float4*)(r0 + 256);
    float4 u2 = *(const float4*)(r0 + 512);
    a0.x += u0.x; a0.y += u0.y; a0.z += u0.z; a0.w += u0.w;
    a1.x += u1.x; a1.y += u1.y; a1.z += u1.z; a1.w += u1.w;
    a2.x += u2.x; a2.y += u2.y; a2.z += u2.z; a2.w += u2.w;
  }

  *(float4*)&sgrp[g][l * 4]       = a0;
  *(float4*)&sgrp[g][256 + l * 4] = a1;
  *(float4*)&sgrp[g][512 + l * 4] = a2;
  __syncthreads();

  float* srow = smean + (size_t)tok * Dv;
#pragma unroll
  for (int s = 0; s < 3; ++s) {
    const int d = tid + s * 256;
    const float v = sgrp[0][d] + sgrp[1][d] + sgrp[2][d] + sgrp[3][d];
    srow[d] = v * m;
  }

  if (tid < 100) {
    x0[(size_t)tok * 256 + tid] = word_W[(size_t)words[tok] * 100 + tid];
  } else if (tid < 150) {
    x0[(size_t)tok * 256 + tid] = pos_W[pos_ids[tok] * 50 + (tid - 100)];
  } else if (tid >= 250) {
    x0[(size_t)tok * 256 + tid] = 0.0f;   // cols 250..255 zero pad
  }
}

// ---------------------------------------------------------------------------
// Prepack: pad mlp1_w [256][250] -> [256][256] with zero columns 250..255.
// ---------------------------------------------------------------------------
__global__ __launch_bounds__(256) void pad_m1(const float* __restrict__ m1w,
                                              float* __restrict__ wpad)
{
  const int idx = blockIdx.x * 256 + threadIdx.x;   // 65536 total
  const int r = idx >> 8, c = idx & 255;
  wpad[idx] = (c < 250) ? m1w[r * 250 + c] : 0.0f;
}

// ---------------------------------------------------------------------------
// Register-tiled fp32 GEMM with register double-buffer prefetch.
// C[M,N] = A[M,K] @ W[N,K]^T (+bias, +relu). Block 256, 64x64 tile, 4x4/thr.
// Next K-chunk's global loads are issued right after the LDS-write barrier,
// so HBM/L2 latency hides under the 16-step FMA loop.
// ---------------------------------------------------------------------------
template<bool BIAS, bool RELU>
__global__ __launch_bounds__(256) void gemm_tn(
    const float* __restrict__ A, int lda,
    const float* __restrict__ W, int ldw,
    const float* __restrict__ bias,
    float* __restrict__ C, int ldc, int c0,
    int N, int K)
{
  const int tid = threadIdx.x;
  const int tm = tid >> 4;          // 0..15
  const int tn = tid & 15;          // 0..15

  __shared__ float sA[16][68];
  __shared__ float sB[16][68];

  float acc[4][4] = {};

  const int row0 = blockIdx.x * 64;
  const int n0 = blockIdx.y * 64;
  const int tok = tid >> 2;         // 0..63 (staging row)
  const int kq = (tid & 3) << 2;    // 0,4,8,12 (staging k offset)

  const bool wvalid = (n0 + tok) < N;
  const float* Ap = A + (size_t)(row0 + tok) * lda + kq;
  const float* Wp = W + (size_t)(wvalid ? (n0 + tok) : 0) * ldw + kq;

  float4 av = *(const float4*)(Ap);
  float4 bv = wvalid ? *(const float4*)(Wp) : float4{0, 0, 0, 0};

  int k0 = 0;
  while (true) {
    __syncthreads();
    sA[kq + 0][tok] = av.x; sA[kq + 1][tok] = av.y;
    sA[kq + 2][tok] = av.z; sA[kq + 3][tok] = av.w;
    sB[kq + 0][tok] = bv.x; sB[kq + 1][tok] = bv.y;
    sB[kq + 2][tok] = bv.z; sB[kq + 3][tok] = bv.w;
    __syncthreads();

    const int kn = k0 + 16;
    const bool more = kn < K;
    if (more) {
      av = *(const float4*)(Ap + kn);
      bv = wvalid ? *(const float4*)(Wp + kn) : float4{0, 0, 0, 0};
    }

#pragma unroll
    for (int kk = 0; kk < 16; ++kk) {
      const float4 a = *(const float4*)&sA[kk][tm * 4];
      const float4 b = *(const float4*)&sB[kk][tn * 4];
      acc[0][0] += a.x * b.x; acc[0][1] += a.x * b.y;
      acc[0][2] += a.x * b.z; acc[0][3] += a.x * b.w;
      acc[1][0] += a.y * b.x; acc[1][1] += a.y * b.y;
      acc[1][2] += a.y * b.z; acc[1][3] += a.y * b.w;
      acc[2][0] += a.z * b.x; acc[2][1] += a.z * b.y;
      acc[2][2] += a.z * b.z; acc[2][3] += a.z * b.w;
      acc[3][0] += a.w * b.x; acc[3][1] += a.w * b.y;
      acc[3][2] += a.w * b.z; acc[3][3] += a.w * b.w;
    }

    if (!more) break;
    k0 = kn;
  }

#pragma unroll
  for (int i = 0; i < 4; ++i) {
    const int row = row0 + tm * 4 + i;
    float* crow = C + (size_t)row * ldc + c0;
#pragma unroll
    for (int j = 0; j < 4; ++j) {
      const int col = n0 + tn * 4 + j;
      if (col < N) {
        float v = acc[i][j];
        if (BIAS) v += bias[col];
        if (RELU) v = fmaxf(v, 0.0f);
        crow[col] = v;
      }
    }
  }
}

// ---------------------------------------------------------------------------
// Fused scores kernel.
//  blocks [0, 512):  arc_scores[b,i,j] = dot(head[b,i], dep[b,j]), 32x32 tile
//  blocks [512, 4608): rel_scores[b,i,j,r] = relh[b,i,r] + reld[b,j,r]
// ---------------------------------------------------------------------------
__global__ __launch_bounds__(256) void fused_scores(
    const float* __restrict__ head, const float* __restrict__ dep,
    const float* __restrict__ relh, const float* __restrict__ reld,
    float* __restrict__ arc_out, float* __restrict__ rel_out)
{
  __shared__ float smem[6450];
  const int tid = threadIdx.x;

  if (blockIdx.x < 512) {
    // ---- arc path ----
    const int blk = blockIdx.x;
    const int b = blk >> 4;
    const int tile = blk & 15;
    const int i0 = (tile >> 2) * 32;
    const int j0 = (tile & 3) * 32;

    float (*sh)[33] = (float(*)[33])smem;          // 32x33
    float (*sd)[33] = (float(*)[33])(smem + 1056); // 32x33

    const int r = tid >> 3;
    const int c = (tid & 7) << 2;
    const int ty = tid >> 4;
    const int tx = tid & 15;

    float acc00 = 0.f, acc01 = 0.f, acc10 = 0.f, acc11 = 0.f;
    const float* hb = head + (size_t)(b * Sv + i0) * Hv;
    const float* db = dep + (size_t)(b * Sv + j0) * Hv;

    for (int k0 = 0; k0 < Hv; k0 += 32) {
      float4 hv = *(const float4*)(hb + (size_t)r * Hv + k0 + c);
      float4 dv = *(const float4*)(db + (size_t)r * Hv + k0 + c);
      __syncthreads();
      sh[r][c] = hv.x; sh[r][c+1] = hv.y; sh[r][c+2] = hv.z; sh[r][c+3] = hv.w;
      sd[r][c] = dv.x; sd[r][c+1] = dv.y; sd[r][c+2] = dv.z; sd[r][c+3] = dv.w;
      __syncthreads();
#pragma unroll
      for (int kk = 0; kk < 32; ++kk) {
        float h0 = sh[ty][kk],  h1 = sh[ty + 16][kk];
        float d0 = sd[tx][kk],  d1 = sd[tx + 16][kk];
        acc00 += h0 * d0; acc01 += h0 * d1;
        acc10 += h1 * d0; acc11 += h1 * d1;
      }
    }

    float* ob = arc_out + (size_t)b * Sv * Sv;
    ob[(i0 + ty) * Sv + j0 + tx]           = acc00;
    ob[(i0 + ty) * Sv + j0 + tx + 16]      = acc01;
    ob[(i0 + ty + 16) * Sv + j0 + tx]      = acc10;
    ob[(i0 + ty + 16) * Sv + j0 + tx + 16] = acc11;
  } else {
    // ---- rel path ----
    const int bi = blockIdx.x - 512;   // b*S + i
    const int b = bi >> 7;

    float* srd = smem;                 // 6400
    float* shi = smem + 6400;          // 50

    const float4* rd4 = (const float4*)(reld + (size_t)b * Sv * Rv);
    float4* s4 = (float4*)srd;
    for (int n = tid; n < (Sv * Rv / 4); n += 256) s4[n] = rd4[n];
    if (tid < Rv) shi[tid] = relh[(size_t)bi * Rv + tid];
    __syncthreads();

    float2* out2 = (float2*)(rel_out + (size_t)bi * Sv * Rv);
    for (int n = tid; n < (Sv * Rv / 2); n += 256) {
      const int j = n / 25;
      const int r = (n - j * 25) * 2;
      const float* rdj = srd + j * Rv;
      float2 v;
      v.x = shi[r]     + rdj[r];
      v.y = shi[r + 1] + rdj[r + 1];
      out2[n] = v;
    }
  }
}

// ---------------------------------------------------------------------------
extern "C" void kernel_launch(void* const* d_in, const int* in_sizes, int n_in,
                              void* d_out, int out_size, void* d_ws, size_t ws_size,
                              hipStream_t stream) {
  const int*   words   = (const int*)d_in[0];
  const int*   pos_ids = (const int*)d_in[1];
  const float* audio   = (const float*)d_in[2];
  const float* st      = (const float*)d_in[3];
  const float* et      = (const float*)d_in[4];
  const float* word_W  = (const float*)d_in[5];
  const float* pos_W   = (const float*)d_in[6];
  const float* audio_w = (const float*)d_in[7];
  const float* audio_b = (const float*)d_in[8];
  const float* m1w     = (const float*)d_in[9];
  const float* m1b     = (const float*)d_in[10];
  const float* m2w     = (const float*)d_in[11];
  const float* m2b     = (const float*)d_in[12];
  const float* aw      = (const float*)d_in[13];
  const float* ab      = (const float*)d_in[14];
  const float* rw      = (const float*)d_in[15];
  const float* rb      = (const float*)d_in[16];

  float* out = (float*)d_out;
  float* ws = (float*)d_ws;

  const size_t NT = (size_t)Bv * Sv;            // 4096 tokens
  float* smean = ws;                            // NT*768
  float* x0    = smean + NT * Dv;               // NT*256
  float* h1    = x0    + NT * 256;              // NT*256
  float* xfeat = h1    + NT * 256;              // NT*256 (dep)
  float* head  = xfeat + NT * 256;              // NT*256
  float* relh  = head  + NT * 256;              // NT*50
  float* reld  = relh  + NT * Rv;               // NT*50
  float* wpad  = reld  + NT * Rv;               // 256*256

  seg_mean<<<(int)NT, 256, 0, stream>>>(
      words, pos_ids, audio, st, et, word_W, pos_W, smean, x0);

  pad_m1<<<256, 256, 0, stream>>>(m1w, wpad);

  // audio projection: x0[:, 150:250] = smean @ audio_w.T + audio_b
  gemm_tn<true, false><<<dim3(64, 2), 256, 0, stream>>>(
      smean, Dv, audio_w, Dv, audio_b, x0, 256, 150, 100, Dv);

  // mlp1: h1 = relu(x0 @ wpad.T + m1b)   (K padded 250->256)
  gemm_tn<true, true><<<dim3(64, 4), 256, 0, stream>>>(
      x0, 256, wpad, 256, m1b, h1, 256, 0, 256, 256);

  // mlp2: xfeat = relu(h1 @ m2w.T + m2b)
  gemm_tn<true, true><<<dim3(64, 4), 256, 0, stream>>>(
      h1, 256, m2w, 256, m2b, xfeat, 256, 0, 256, 256);

  // arc head: head = xfeat @ aw.T + ab
  gemm_tn<true, false><<<dim3(64, 4), 256, 0, stream>>>(
      xfeat, 256, aw, 256, ab, head, 256, 0, 256, 256);

  // rel projections
  gemm_tn<true, false><<<dim3(64, 1), 256, 0, stream>>>(
      head, 256, rw, 2 * Hv, rb, relh, Rv, 0, Rv, 256);
  gemm_tn<false, false><<<dim3(64, 1), 256, 0, stream>>>(
      xfeat, 256, rw + Hv, 2 * Hv, (const float*)nullptr, reld, Rv, 0, Rv, 256);

  fused_scores<<<512 + (int)NT, 256, 0, stream>>>(
      head, xfeat, relh, reld, out, out + (size_t)Bv * Sv * Sv);
}